// Round 4
// baseline (2148.079 us; speedup 1.0000x reference)
//
#include <hip/hip_runtime.h>
#include <hip/hip_bf16.h>
#include <math.h>

#define BB 8
#define NN 2048
#define KK 10
#define EPSF 1e-5f
#define NEG_SLOPE 0.2f

// ---------------- xx[n] = sum_c x[n,c]^2 ----------------
__global__ void xx_kernel(const float* __restrict__ x, float* __restrict__ xx, int C) {
    int i = blockIdx.x * blockDim.x + threadIdx.x;
    if (i >= BB * NN) return;
    const float* row = x + (size_t)i * C;
    float s = 0.f;
    for (int c = 0; c < C; ++c) { float v = row[c]; s = fmaf(v, v, s); }
    xx[i] = s;
}

// ---------------- fused dist GEMM + running exact top-10 ----------------
// Block = (j-half, i-tile of 64 rows, batch). Streams 16 j-tiles of 64; for
// each tile computes dist values with the SAME fma order / correction
// association as round-3 dist_gemm (bit-identical values -> identical
// neighbor indices), then updates per-row sorted top-10 lists in LDS.
// List semantics: sorted by (value desc, index asc) == jax.lax.top_k.
// Wave w owns rows [16w,16w+16) (it also computes/writes exactly those rows
// of Ds), so the update needs no cross-wave sync beyond the staging barriers.
__global__ __launch_bounds__(256) void knn_fused_kernel(
    const float* __restrict__ x, const float* __restrict__ xx,
    float* __restrict__ hlv, int* __restrict__ hlj, int C) {
    int b = blockIdx.z;
    int i0 = blockIdx.y << 6;
    int half = blockIdx.x;          // j in [half*1024, half*1024+1024)
    const float* xb = x + (size_t)b * NN * C;
    const float* xxb = xx + (size_t)b * NN;
    __shared__ float As[16][68], Bs[16][68];
    __shared__ float Ds[64][68];
    __shared__ float Lv[64][10];
    __shared__ int   Lj[64][10];
    __shared__ float Thv[64];       // current 10th value per row
    __shared__ int   Thj[64];       // current 10th index per row
    int tid = threadIdx.x;
    int tx = tid & 15, ty = tid >> 4;
    int wid = tid >> 6, t = tid & 63;

    for (int l = tid; l < 640; l += 256) {
        ((float*)Lv)[l] = -INFINITY;
        ((int*)Lj)[l] = 0x7fffffff;
    }
    if (tid < 64) { Thv[tid] = -INFINITY; Thj[tid] = 0x7fffffff; }

    float xi[4];
    #pragma unroll
    for (int u = 0; u < 4; ++u) xi[u] = xxb[i0 + (ty << 2) + u];
    __syncthreads();

    for (int jt = 0; jt < 16; ++jt) {
        int j0 = (half << 10) + (jt << 6);
        float acc[4][4] = {};
        for (int k0 = 0; k0 < C; k0 += 16) {
            #pragma unroll
            for (int l = tid; l < 1024; l += 256) {
                int r = l >> 4, c = l & 15;
                int kc = k0 + c;
                As[c][r] = (kc < C) ? xb[(size_t)(i0 + r) * C + kc] : 0.f;
                Bs[c][r] = (kc < C) ? xb[(size_t)(j0 + r) * C + kc] : 0.f;
            }
            __syncthreads();
            #pragma unroll
            for (int kk = 0; kk < 16; ++kk) {
                float4 a4 = *(const float4*)&As[kk][ty << 2];
                float4 b4 = *(const float4*)&Bs[kk][tx << 2];
                float a[4] = {a4.x, a4.y, a4.z, a4.w};
                float bv[4] = {b4.x, b4.y, b4.z, b4.w};
                #pragma unroll
                for (int u = 0; u < 4; ++u)
                    #pragma unroll
                    for (int v = 0; v < 4; ++v)
                        acc[u][v] = fmaf(a[u], bv[v], acc[u][v]);
            }
            __syncthreads();
        }
        float xj[4];
        #pragma unroll
        for (int v = 0; v < 4; ++v) xj[v] = xxb[j0 + (tx << 2) + v];
        #pragma unroll
        for (int u = 0; u < 4; ++u) {
            int row = (ty << 2) + u;
            float4 o;
            o.x = 2.f * acc[u][0] - xi[u] - xj[0];
            o.y = 2.f * acc[u][1] - xi[u] - xj[1];
            o.z = 2.f * acc[u][2] - xi[u] - xj[2];
            o.w = 2.f * acc[u][3] - xi[u] - xj[3];
            *(float4*)&Ds[row][tx << 2] = o;
        }
        __syncthreads();   // make Ds visible (cheap safety; cross-lane LDS)

        // per-wave top-10 update for its 16 rows
        #pragma unroll 1
        for (int r16 = 0; r16 < 16; ++r16) {
            int row = (wid << 4) + r16;
            float cv = Ds[row][t];
            int   cj = j0 + t;
            float v9 = Thv[row]; int j9 = Thj[row];   // LDS broadcast
            bool beat = (cv > v9) || (cv == v9 && cj < j9);
            unsigned long long m = __ballot(beat);
            if (m == 0ULL) continue;                  // wave-uniform
            float lv = -INFINITY; int lj = 0x7fffffff;
            if (t < 10) { lv = Lv[row][t]; lj = Lj[row][t]; }
            while (m) {
                int src = (int)__ffsll((unsigned long long)m) - 1;
                m &= m - 1ULL;
                float bv = __shfl(cv, src);
                int   bj = __shfl(cj, src);
                if ((bv > v9) || (bv == v9 && bj < j9)) {  // re-check vs risen threshold
                    float pv = __shfl_up(lv, 1);
                    int   pj = __shfl_up(lj, 1);
                    bool cbp  = (bv > lv) || (bv == lv && bj < lj);          // beats slot p
                    bool cbpm = (t > 0) && ((bv > pv) || (bv == pv && bj < pj)); // beats slot p-1
                    lv = cbp ? (cbpm ? pv : bv) : lv;
                    lj = cbp ? (cbpm ? pj : bj) : lj;
                    v9 = __shfl(lv, 9);
                    j9 = __shfl(lj, 9);
                }
            }
            if (t < 10) { Lv[row][t] = lv; Lj[row][t] = lj; }
            if (t == 0) { Thv[row] = v9; Thj[row] = j9; }
        }
    }

    // write this half's top-10 lists
    #pragma unroll 1
    for (int r16 = 0; r16 < 16; ++r16) {
        int row = (wid << 4) + r16;
        if (t < 10) {
            size_t base = (((size_t)b * NN + i0 + row) * 2 + half) * 10;
            hlv[base + t] = Lv[row][t];
            hlj[base + t] = Lj[row][t];
        }
    }
}

// ---------------- merge two half top-10 lists -> final indices ----------------
// Exact: top-10 of a row == top-10 of (union of the two half top-10s).
// Successor scan over 20 candidates in (v desc, j asc) total order.
__global__ __launch_bounds__(256) void topk_merge_kernel(
    const float* __restrict__ hlv, const int* __restrict__ hlj,
    int* __restrict__ idxout) {
    int row = blockIdx.x * 256 + threadIdx.x;   // [0, BB*NN)
    float v[20]; int j[20];
    size_t base = (size_t)row * 20;
    #pragma unroll
    for (int e = 0; e < 20; ++e) { v[e] = hlv[base + e]; j[e] = hlj[base + e]; }
    int* out = idxout + (size_t)row * KK;
    float lastv = INFINITY; int lastj = -1;
    for (int r = 0; r < KK; ++r) {
        float bv = -INFINITY; int bj = 0x7fffffff;
        #pragma unroll
        for (int e = 0; e < 20; ++e) {
            bool elig = (v[e] < lastv) || (v[e] == lastv && j[e] > lastj);
            bool better = elig && ((v[e] > bv) || (v[e] == bv && j[e] < bj));
            bv = better ? v[e] : bv;
            bj = better ? j[e] : bj;
        }
        out[r] = bj;
        lastv = bv; lastj = bj;
    }
}

// ---------------- y,z = X*W1^T, X*W2^T as one tiled GEMM ----------------
__global__ __launch_bounds__(256) void yz_gemm_kernel(
    const float* __restrict__ x, const float* __restrict__ w,
    float* __restrict__ y, float* __restrict__ z, int C, int co) {
    int n0 = blockIdx.y << 6;     // point tile
    int oc0 = blockIdx.x << 6;    // combined output-channel tile
    __shared__ float As[16][68], Bs[16][68];
    int tid = threadIdx.x;
    int tx = tid & 15, ty = tid >> 4;
    float acc[4][4] = {};
    for (int k0 = 0; k0 < C; k0 += 16) {
        #pragma unroll
        for (int l = tid; l < 1024; l += 256) {
            int r = l >> 4, c = l & 15;
            int kc = k0 + c;
            As[c][r] = (kc < C) ? x[(size_t)(n0 + r) * C + kc] : 0.f;
            float bvv = 0.f;
            if (kc < C) {
                int oc = oc0 + r;
                int wrow = (oc < co) ? oc : (oc - co);
                int wcol = (oc < co) ? kc : (C + kc);
                bvv = w[(size_t)wrow * 2 * C + wcol];
            }
            Bs[c][r] = bvv;
        }
        __syncthreads();
        #pragma unroll
        for (int kk = 0; kk < 16; ++kk) {
            float4 a4 = *(const float4*)&As[kk][ty << 2];
            float4 b4 = *(const float4*)&Bs[kk][tx << 2];
            float a[4] = {a4.x, a4.y, a4.z, a4.w};
            float bv[4] = {b4.x, b4.y, b4.z, b4.w};
            #pragma unroll
            for (int u = 0; u < 4; ++u)
                #pragma unroll
                for (int v = 0; v < 4; ++v)
                    acc[u][v] = fmaf(a[u], bv[v], acc[u][v]);
        }
        __syncthreads();
    }
    bool isY = (oc0 < co);
    float* dst = isY ? y : z;
    int c0 = isY ? oc0 : (oc0 - co);
    #pragma unroll
    for (int u = 0; u < 4; ++u) {
        int n = n0 + (ty << 2) + u;
        float4 o;
        o.x = acc[u][0]; o.y = acc[u][1]; o.z = acc[u][2]; o.w = acc[u][3];
        *(float4*)&dst[(size_t)n * co + c0 + (tx << 2)] = o;
    }
}

// ---------------- gather + max_k + BN + lrelu ----------------
__global__ void edge_apply_kernel(const float* __restrict__ y, const float* __restrict__ z,
    const int* __restrict__ idx, const float* __restrict__ g, const float* __restrict__ be,
    const float* __restrict__ rm, const float* __restrict__ rv,
    float* __restrict__ out, int co) {
    int n = blockIdx.x;   // global point id in [0, B*N)
    int o = threadIdx.x;
    int b = n >> 11;      // N = 2048
    __shared__ int sj[KK];
    if (o < KK) sj[o] = idx[(size_t)n * KK + o];
    __syncthreads();
    float yn = y[(size_t)n * co + o], zn = z[(size_t)n * co + o];
    float mx = -INFINITY, mn = INFINITY;
    #pragma unroll
    for (int j = 0; j < KK; ++j) {
        float v = y[((size_t)b * NN + sj[j]) * co + o];
        mx = fmaxf(mx, v);
        mn = fminf(mn, v);
    }
    float s = g[o] * rsqrtf(rv[o] + EPSF);
    float tt = be[o] - rm[o] * s;
    float ybest = (s >= 0.f) ? mx : mn;
    float h = fmaf(s, ybest - yn + zn, tt);
    out[(size_t)n * co + o] = (h >= 0.f) ? h : NEG_SLOPE * h;
}

// ---------------- global max over N of concat(x1..x4) ----------------
#define NSPLIT 32
__global__ void gmax_partial(const float* __restrict__ x1, const float* __restrict__ x2,
                             const float* __restrict__ x3, const float* __restrict__ x4,
                             float* __restrict__ part) {
    int ch = threadIdx.x;            // 0..511
    int split = blockIdx.x, b = blockIdx.y;
    int n0 = split * (NN / NSPLIT);
    float m = -INFINITY;
    for (int q = 0; q < NN / NSPLIT; ++q) {
        int n = b * NN + n0 + q;
        float v;
        if (ch < 64)       v = x1[(size_t)n * 64 + ch];
        else if (ch < 128) v = x2[(size_t)n * 64 + (ch - 64)];
        else if (ch < 256) v = x3[(size_t)n * 128 + (ch - 128)];
        else               v = x4[(size_t)n * 256 + (ch - 256)];
        m = fmaxf(m, v);
    }
    part[((size_t)split * BB + b) * 512 + ch] = m;
}

__global__ void gmax_final(const float* __restrict__ part, float* __restrict__ xg) {
    int ch = threadIdx.x, b = blockIdx.x;
    float m = -INFINITY;
    for (int s = 0; s < NSPLIT; ++s) m = fmaxf(m, part[((size_t)s * BB + b) * 512 + ch]);
    xg[(size_t)b * 512 + ch] = m;
}

// ---------------- final linear + BN + lrelu ----------------
__global__ void linear_kernel(const float* __restrict__ xg, const float* __restrict__ lw,
    const float* __restrict__ lb, const float* __restrict__ g5, const float* __restrict__ b5,
    const float* __restrict__ rm5, const float* __restrict__ rv5, float* __restrict__ out0) {
    int o = blockIdx.x * 256 + threadIdx.x;
    int b = blockIdx.y;
    __shared__ float xs[512];
    for (int l = threadIdx.x; l < 512; l += 256) xs[l] = xg[(size_t)b * 512 + l];
    __syncthreads();
    float acc = 0.f;
    const float* wr = lw + (size_t)o * 512;
    for (int c = 0; c < 512; ++c) acc = fmaf(xs[c], wr[c], acc);
    acc += lb[o];
    float s = g5[o] * rsqrtf(rv5[o] + EPSF);
    float h = fmaf(s, acc - rm5[o], b5[o]);
    out0[(size_t)b * 1024 + o] = (h >= 0.f) ? h : NEG_SLOPE * h;
}

// ---------------- x4 (B,N,256) -> out1 (B,256,N) ----------------
__global__ void transpose_kernel(const float* __restrict__ x4, float* __restrict__ out1) {
    __shared__ float tile[32][33];
    int b = blockIdx.z;
    int nb = blockIdx.x * 32, ob = blockIdx.y * 32;
    int tx = threadIdx.x, ty = threadIdx.y;  // (32, 8)
    #pragma unroll
    for (int r = 0; r < 4; ++r) {
        int o = ob + tx;
        int n = nb + ty + r * 8;
        tile[ty + r * 8][tx] = x4[((size_t)b * NN + n) * 256 + o];
    }
    __syncthreads();
    #pragma unroll
    for (int r = 0; r < 4; ++r) {
        int n = nb + tx;
        int o = ob + ty + r * 8;
        out1[((size_t)b * 256 + o) * NN + n] = tile[tx][ty + r * 8];
    }
}

extern "C" void kernel_launch(void* const* d_in, const int* in_sizes, int n_in,
                              void* d_out, int out_size, void* d_ws, size_t ws_size,
                              hipStream_t stream) {
    const float* x = (const float*)d_in[0];
    const float* lin_w = (const float*)d_in[21];
    const float* lin_b = (const float*)d_in[22];
    const float* g5 = (const float*)d_in[23];
    const float* b5 = (const float*)d_in[24];
    const float* rm5 = (const float*)d_in[25];
    const float* rv5 = (const float*)d_in[26];

    // ---- workspace bump allocation ----
    size_t off = 0;
    auto alloc = [&](size_t nbytes) {
        void* r = (char*)d_ws + off;
        off += (nbytes + 255) & ~(size_t)255;
        return r;
    };
    const size_t PTS = (size_t)BB * NN;
    float* xx   = (float*)alloc(PTS * 4);
    int*   idx  = (int*)  alloc(PTS * KK * 4);
    float* y    = (float*)alloc(PTS * 256 * 4);
    float* z    = (float*)alloc(PTS * 256 * 4);
    float* x1   = (float*)alloc(PTS * 64 * 4);
    float* x2   = (float*)alloc(PTS * 64 * 4);
    float* x3   = (float*)alloc(PTS * 128 * 4);
    float* x4   = (float*)alloc(PTS * 256 * 4);
    float* part = (float*)alloc((size_t)NSPLIT * BB * 512 * 4);
    float* xg   = (float*)alloc((size_t)BB * 512 * 4);
    float* hlv  = (float*)alloc(PTS * 20 * 4);
    int*   hlj  = (int*)  alloc(PTS * 20 * 4);

    const int CI[4] = {5, 64, 64, 128};
    const int CO[4] = {64, 64, 128, 256};
    const float* xin = x;
    float* xout[4] = {x1, x2, x3, x4};

    for (int l = 0; l < 4; ++l) {
        int C = CI[l], co = CO[l];
        const float* w  = (const float*)d_in[1 + l * 5 + 0];
        const float* g  = (const float*)d_in[1 + l * 5 + 1];
        const float* be = (const float*)d_in[1 + l * 5 + 2];
        const float* rm = (const float*)d_in[1 + l * 5 + 3];
        const float* rv = (const float*)d_in[1 + l * 5 + 4];

        xx_kernel<<<(BB * NN + 255) / 256, 256, 0, stream>>>(xin, xx, C);
        knn_fused_kernel<<<dim3(2, NN / 64, BB), 256, 0, stream>>>(xin, xx, hlv, hlj, C);
        topk_merge_kernel<<<(int)(PTS / 256), 256, 0, stream>>>(hlv, hlj, idx);

        yz_gemm_kernel<<<dim3(2 * co / 64, (int)(PTS / 64)), 256, 0, stream>>>(
            xin, w, y, z, C, co);
        edge_apply_kernel<<<(int)PTS, co, 0, stream>>>(y, z, idx, g, be, rm, rv, xout[l], co);
        xin = xout[l];
    }

    gmax_partial<<<dim3(NSPLIT, BB), 512, 0, stream>>>(x1, x2, x3, x4, part);
    gmax_final<<<BB, 512, 0, stream>>>(part, xg);
    linear_kernel<<<dim3(1024 / 256, BB), 256, 0, stream>>>(
        xg, lin_w, lin_b, g5, b5, rm5, rv5, (float*)d_out);
    transpose_kernel<<<dim3(NN / 32, 256 / 32, BB), dim3(32, 8), 0, stream>>>(
        x4, (float*)d_out + (size_t)BB * 1024);
}

// Round 5
// 1464.435 us; speedup vs baseline: 1.4668x; 1.4668x over previous
//
#include <hip/hip_runtime.h>
#include <hip/hip_bf16.h>
#include <math.h>

#define BB 8
#define NN 2048
#define KK 10
#define QSPLIT 4
#define JT_PER (NN / 64 / QSPLIT)   // 8 j-tiles per block
#define EPSF 1e-5f
#define NEG_SLOPE 0.2f

// ---------------- xx[n] = sum_c x[n,c]^2 ----------------
__global__ void xx_kernel(const float* __restrict__ x, float* __restrict__ xx, int C) {
    int i = blockIdx.x * blockDim.x + threadIdx.x;
    if (i >= BB * NN) return;
    const float* row = x + (size_t)i * C;
    float s = 0.f;
    for (int c = 0; c < C; ++c) { float v = row[c]; s = fmaf(v, v, s); }
    xx[i] = s;
}

// ---------------- fused dist GEMM + exact top-10 (register lists) ----------------
// Block = (j-quarter, i-tile of 64 rows, batch). Streams 8 j-tiles of 64.
// GEMM phase: identical fma order/association as round-3 dist_gemm ->
// bit-identical dist values -> identical neighbor ordering.
// Update phase: 4 threads per row, each owns 16 columns of the Ds tile and a
// per-thread sorted top-10 in REGISTERS (value desc, index asc). Branchy
// bubble-insert, no cross-lane ops (round-4's dependent-shfl chain was the
// 547us disaster). End: 4-pointer in-LDS merge -> one sorted 10-list per
// (row, quarter), written to hl*.
__global__ __launch_bounds__(256) void knn_fused_kernel(
    const float* __restrict__ x, const float* __restrict__ xx,
    float* __restrict__ hlv, int* __restrict__ hlj, int C) {
    int b = blockIdx.z;
    int i0 = blockIdx.y << 6;
    int qs = blockIdx.x;
    const float* xb = x + (size_t)b * NN * C;
    const float* xxb = xx + (size_t)b * NN;
    __shared__ union {
        struct { float As[16][68]; float Bs[16][68]; float Ds[64][68]; } g;
        struct { float Mv[64][4 * KK]; int Mj[64][4 * KK]; } m;
    } S;
    int tid = threadIdx.x;
    int tx = tid & 15, ty = tid >> 4;      // GEMM mapping
    int row = tid >> 2, q = tid & 3;       // update mapping (same wave owns same rows)

    float lv[KK]; int lj[KK];
    #pragma unroll
    for (int e = 0; e < KK; ++e) { lv[e] = -INFINITY; lj[e] = 0x7fffffff; }

    float xi[4];
    #pragma unroll
    for (int u = 0; u < 4; ++u) xi[u] = xxb[i0 + (ty << 2) + u];

    for (int jt = 0; jt < JT_PER; ++jt) {
        int j0 = ((qs * JT_PER + jt) << 6);
        float acc[4][4] = {};
        for (int k0 = 0; k0 < C; k0 += 16) {
            #pragma unroll
            for (int l = tid; l < 1024; l += 256) {
                int r = l >> 4, c = l & 15;
                int kc = k0 + c;
                S.g.As[c][r] = (kc < C) ? xb[(size_t)(i0 + r) * C + kc] : 0.f;
                S.g.Bs[c][r] = (kc < C) ? xb[(size_t)(j0 + r) * C + kc] : 0.f;
            }
            __syncthreads();
            #pragma unroll
            for (int kk = 0; kk < 16; ++kk) {
                float4 a4 = *(const float4*)&S.g.As[kk][ty << 2];
                float4 b4 = *(const float4*)&S.g.Bs[kk][tx << 2];
                float a[4] = {a4.x, a4.y, a4.z, a4.w};
                float bv[4] = {b4.x, b4.y, b4.z, b4.w};
                #pragma unroll
                for (int u = 0; u < 4; ++u)
                    #pragma unroll
                    for (int v = 0; v < 4; ++v)
                        acc[u][v] = fmaf(a[u], bv[v], acc[u][v]);
            }
            __syncthreads();
        }
        float xj[4];
        #pragma unroll
        for (int v = 0; v < 4; ++v) xj[v] = xxb[j0 + (tx << 2) + v];
        #pragma unroll
        for (int u = 0; u < 4; ++u) {
            int rw = (ty << 2) + u;
            float4 o;
            o.x = 2.f * acc[u][0] - xi[u] - xj[0];
            o.y = 2.f * acc[u][1] - xi[u] - xj[1];
            o.z = 2.f * acc[u][2] - xi[u] - xj[2];
            o.w = 2.f * acc[u][3] - xi[u] - xj[3];
            *(float4*)&S.g.Ds[rw][tx << 2] = o;
        }
        __syncthreads();

        // per-thread scan of 16 owned columns (4x float4 LDS reads)
        int cbase = q << 4;
        #pragma unroll
        for (int s4 = 0; s4 < 4; ++s4) {
            float4 d4 = *(const float4*)&S.g.Ds[row][cbase + (s4 << 2)];
            float dv[4] = {d4.x, d4.y, d4.z, d4.w};
            #pragma unroll
            for (int e4 = 0; e4 < 4; ++e4) {
                float cv = dv[e4];
                int cj = j0 + cbase + (s4 << 2) + e4;
                if ((cv > lv[KK - 1]) || (cv == lv[KK - 1] && cj < lj[KK - 1])) {
                    lv[KK - 1] = cv; lj[KK - 1] = cj;
                    #pragma unroll
                    for (int e = KK - 1; e > 0; --e) {
                        bool sw = (lv[e] > lv[e - 1]) ||
                                  (lv[e] == lv[e - 1] && lj[e] < lj[e - 1]);
                        float av = lv[e - 1], bw = lv[e];
                        int aj = lj[e - 1], bj = lj[e];
                        lv[e - 1] = sw ? bw : av;  lv[e] = sw ? av : bw;
                        lj[e - 1] = sw ? bj : aj;  lj[e] = sw ? aj : bj;
                    }
                }
            }
        }
        __syncthreads();   // Ds rewritten next jt; As/Bs barrier also follows
    }

    // ---- merge 4 thread-lists per row -> sorted quarter list ----
    __syncthreads();       // retire all aliased As/Bs/Ds use before Mv/Mj
    #pragma unroll
    for (int e = 0; e < KK; ++e) {
        S.m.Mv[row][q * KK + e] = lv[e];
        S.m.Mj[row][q * KK + e] = lj[e];
    }
    __syncthreads();
    if (q == 0) {
        float hv[4]; int hj[4]; int p[4];
        #pragma unroll
        for (int e = 0; e < 4; ++e) {
            p[e] = 0;
            hv[e] = S.m.Mv[row][e * KK];
            hj[e] = S.m.Mj[row][e * KK];
        }
        size_t base = (((size_t)b * NN + i0 + row) * QSPLIT + qs) * KK;
        for (int r = 0; r < KK; ++r) {
            float bv = hv[0]; int bj = hj[0]; int L = 0;
            #pragma unroll
            for (int e = 1; e < 4; ++e) {
                bool bt = (hv[e] > bv) || (hv[e] == bv && hj[e] < bj);
                bv = bt ? hv[e] : bv; bj = bt ? hj[e] : bj; L = bt ? e : L;
            }
            hlv[base + r] = bv;
            hlj[base + r] = bj;
            #pragma unroll
            for (int e = 0; e < 4; ++e) {
                if (e == L) {
                    ++p[e];
                    bool ok = p[e] < KK;
                    hv[e] = ok ? S.m.Mv[row][e * KK + p[e]] : -INFINITY;
                    hj[e] = ok ? S.m.Mj[row][e * KK + p[e]] : 0x7fffffff;
                }
            }
        }
    }
}

// ---------------- final merge: 4 sorted quarter-lists -> top-10 indices ----------------
// Quarters cover disjoint j ranges; top-10 of union of quarter top-10s is exact.
__global__ __launch_bounds__(256) void topk_merge_kernel(
    const float* __restrict__ hlv, const int* __restrict__ hlj,
    int* __restrict__ idxout) {
    int row = blockIdx.x * 256 + threadIdx.x;   // [0, BB*NN)
    size_t base = (size_t)row * (QSPLIT * KK);
    float hv[QSPLIT]; int hj[QSPLIT]; int p[QSPLIT];
    #pragma unroll
    for (int e = 0; e < QSPLIT; ++e) {
        p[e] = 0;
        hv[e] = hlv[base + e * KK];
        hj[e] = hlj[base + e * KK];
    }
    int* out = idxout + (size_t)row * KK;
    for (int r = 0; r < KK; ++r) {
        float bv = hv[0]; int bj = hj[0]; int L = 0;
        #pragma unroll
        for (int e = 1; e < QSPLIT; ++e) {
            bool bt = (hv[e] > bv) || (hv[e] == bv && hj[e] < bj);
            bv = bt ? hv[e] : bv; bj = bt ? hj[e] : bj; L = bt ? e : L;
        }
        out[r] = bj;
        #pragma unroll
        for (int e = 0; e < QSPLIT; ++e) {
            if (e == L) {
                ++p[e];
                bool ok = p[e] < KK;
                hv[e] = ok ? hlv[base + e * KK + p[e]] : -INFINITY;
                hj[e] = ok ? hlj[base + e * KK + p[e]] : 0x7fffffff;
            }
        }
    }
}

// ---------------- y,z = X*W1^T, X*W2^T as one tiled GEMM ----------------
__global__ __launch_bounds__(256) void yz_gemm_kernel(
    const float* __restrict__ x, const float* __restrict__ w,
    float* __restrict__ y, float* __restrict__ z, int C, int co) {
    int n0 = blockIdx.y << 6;     // point tile
    int oc0 = blockIdx.x << 6;    // combined output-channel tile
    __shared__ float As[16][68], Bs[16][68];
    int tid = threadIdx.x;
    int tx = tid & 15, ty = tid >> 4;
    float acc[4][4] = {};
    for (int k0 = 0; k0 < C; k0 += 16) {
        #pragma unroll
        for (int l = tid; l < 1024; l += 256) {
            int r = l >> 4, c = l & 15;
            int kc = k0 + c;
            As[c][r] = (kc < C) ? x[(size_t)(n0 + r) * C + kc] : 0.f;
            float bvv = 0.f;
            if (kc < C) {
                int oc = oc0 + r;
                int wrow = (oc < co) ? oc : (oc - co);
                int wcol = (oc < co) ? kc : (C + kc);
                bvv = w[(size_t)wrow * 2 * C + wcol];
            }
            Bs[c][r] = bvv;
        }
        __syncthreads();
        #pragma unroll
        for (int kk = 0; kk < 16; ++kk) {
            float4 a4 = *(const float4*)&As[kk][ty << 2];
            float4 b4 = *(const float4*)&Bs[kk][tx << 2];
            float a[4] = {a4.x, a4.y, a4.z, a4.w};
            float bv[4] = {b4.x, b4.y, b4.z, b4.w};
            #pragma unroll
            for (int u = 0; u < 4; ++u)
                #pragma unroll
                for (int v = 0; v < 4; ++v)
                    acc[u][v] = fmaf(a[u], bv[v], acc[u][v]);
        }
        __syncthreads();
    }
    bool isY = (oc0 < co);
    float* dst = isY ? y : z;
    int c0 = isY ? oc0 : (oc0 - co);
    #pragma unroll
    for (int u = 0; u < 4; ++u) {
        int n = n0 + (ty << 2) + u;
        float4 o;
        o.x = acc[u][0]; o.y = acc[u][1]; o.z = acc[u][2]; o.w = acc[u][3];
        *(float4*)&dst[(size_t)n * co + c0 + (tx << 2)] = o;
    }
}

// ---------------- gather + max_k + BN + lrelu ----------------
__global__ void edge_apply_kernel(const float* __restrict__ y, const float* __restrict__ z,
    const int* __restrict__ idx, const float* __restrict__ g, const float* __restrict__ be,
    const float* __restrict__ rm, const float* __restrict__ rv,
    float* __restrict__ out, int co) {
    int n = blockIdx.x;   // global point id in [0, B*N)
    int o = threadIdx.x;
    int b = n >> 11;      // N = 2048
    __shared__ int sj[KK];
    if (o < KK) sj[o] = idx[(size_t)n * KK + o];
    __syncthreads();
    float yn = y[(size_t)n * co + o], zn = z[(size_t)n * co + o];
    float mx = -INFINITY, mn = INFINITY;
    #pragma unroll
    for (int j = 0; j < KK; ++j) {
        float v = y[((size_t)b * NN + sj[j]) * co + o];
        mx = fmaxf(mx, v);
        mn = fminf(mn, v);
    }
    float s = g[o] * rsqrtf(rv[o] + EPSF);
    float tt = be[o] - rm[o] * s;
    float ybest = (s >= 0.f) ? mx : mn;
    float h = fmaf(s, ybest - yn + zn, tt);
    out[(size_t)n * co + o] = (h >= 0.f) ? h : NEG_SLOPE * h;
}

// ---------------- global max over N of concat(x1..x4) ----------------
#define NSPLIT 32
__global__ void gmax_partial(const float* __restrict__ x1, const float* __restrict__ x2,
                             const float* __restrict__ x3, const float* __restrict__ x4,
                             float* __restrict__ part) {
    int ch = threadIdx.x;            // 0..511
    int split = blockIdx.x, b = blockIdx.y;
    int n0 = split * (NN / NSPLIT);
    float m = -INFINITY;
    for (int q = 0; q < NN / NSPLIT; ++q) {
        int n = b * NN + n0 + q;
        float v;
        if (ch < 64)       v = x1[(size_t)n * 64 + ch];
        else if (ch < 128) v = x2[(size_t)n * 64 + (ch - 64)];
        else if (ch < 256) v = x3[(size_t)n * 128 + (ch - 128)];
        else               v = x4[(size_t)n * 256 + (ch - 256)];
        m = fmaxf(m, v);
    }
    part[((size_t)split * BB + b) * 512 + ch] = m;
}

__global__ void gmax_final(const float* __restrict__ part, float* __restrict__ xg) {
    int ch = threadIdx.x, b = blockIdx.x;
    float m = -INFINITY;
    for (int s = 0; s < NSPLIT; ++s) m = fmaxf(m, part[((size_t)s * BB + b) * 512 + ch]);
    xg[(size_t)b * 512 + ch] = m;
}

// ---------------- final linear + BN + lrelu ----------------
__global__ void linear_kernel(const float* __restrict__ xg, const float* __restrict__ lw,
    const float* __restrict__ lb, const float* __restrict__ g5, const float* __restrict__ b5,
    const float* __restrict__ rm5, const float* __restrict__ rv5, float* __restrict__ out0) {
    int o = blockIdx.x * 256 + threadIdx.x;
    int b = blockIdx.y;
    __shared__ float xs[512];
    for (int l = threadIdx.x; l < 512; l += 256) xs[l] = xg[(size_t)b * 512 + l];
    __syncthreads();
    float acc = 0.f;
    const float* wr = lw + (size_t)o * 512;
    for (int c = 0; c < 512; ++c) acc = fmaf(xs[c], wr[c], acc);
    acc += lb[o];
    float s = g5[o] * rsqrtf(rv5[o] + EPSF);
    float h = fmaf(s, acc - rm5[o], b5[o]);
    out0[(size_t)b * 1024 + o] = (h >= 0.f) ? h : NEG_SLOPE * h;
}

// ---------------- x4 (B,N,256) -> out1 (B,256,N) ----------------
__global__ void transpose_kernel(const float* __restrict__ x4, float* __restrict__ out1) {
    __shared__ float tile[32][33];
    int b = blockIdx.z;
    int nb = blockIdx.x * 32, ob = blockIdx.y * 32;
    int tx = threadIdx.x, ty = threadIdx.y;  // (32, 8)
    #pragma unroll
    for (int r = 0; r < 4; ++r) {
        int o = ob + tx;
        int n = nb + ty + r * 8;
        tile[ty + r * 8][tx] = x4[((size_t)b * NN + n) * 256 + o];
    }
    __syncthreads();
    #pragma unroll
    for (int r = 0; r < 4; ++r) {
        int n = nb + tx;
        int o = ob + ty + r * 8;
        out1[((size_t)b * 256 + o) * NN + n] = tile[tx][ty + r * 8];
    }
}

extern "C" void kernel_launch(void* const* d_in, const int* in_sizes, int n_in,
                              void* d_out, int out_size, void* d_ws, size_t ws_size,
                              hipStream_t stream) {
    const float* x = (const float*)d_in[0];
    const float* lin_w = (const float*)d_in[21];
    const float* lin_b = (const float*)d_in[22];
    const float* g5 = (const float*)d_in[23];
    const float* b5 = (const float*)d_in[24];
    const float* rm5 = (const float*)d_in[25];
    const float* rv5 = (const float*)d_in[26];

    // ---- workspace bump allocation ----
    size_t off = 0;
    auto alloc = [&](size_t nbytes) {
        void* r = (char*)d_ws + off;
        off += (nbytes + 255) & ~(size_t)255;
        return r;
    };
    const size_t PTS = (size_t)BB * NN;
    float* xx   = (float*)alloc(PTS * 4);
    int*   idx  = (int*)  alloc(PTS * KK * 4);
    float* y    = (float*)alloc(PTS * 256 * 4);
    float* z    = (float*)alloc(PTS * 256 * 4);
    float* x1   = (float*)alloc(PTS * 64 * 4);
    float* x2   = (float*)alloc(PTS * 64 * 4);
    float* x3   = (float*)alloc(PTS * 128 * 4);
    float* x4   = (float*)alloc(PTS * 256 * 4);
    float* part = (float*)alloc((size_t)NSPLIT * BB * 512 * 4);
    float* xg   = (float*)alloc((size_t)BB * 512 * 4);
    float* hlv  = (float*)alloc(PTS * QSPLIT * KK * 4);
    int*   hlj  = (int*)  alloc(PTS * QSPLIT * KK * 4);

    const int CI[4] = {5, 64, 64, 128};
    const int CO[4] = {64, 64, 128, 256};
    const float* xin = x;
    float* xout[4] = {x1, x2, x3, x4};

    for (int l = 0; l < 4; ++l) {
        int C = CI[l], co = CO[l];
        const float* w  = (const float*)d_in[1 + l * 5 + 0];
        const float* g  = (const float*)d_in[1 + l * 5 + 1];
        const float* be = (const float*)d_in[1 + l * 5 + 2];
        const float* rm = (const float*)d_in[1 + l * 5 + 3];
        const float* rv = (const float*)d_in[1 + l * 5 + 4];

        xx_kernel<<<(BB * NN + 255) / 256, 256, 0, stream>>>(xin, xx, C);
        knn_fused_kernel<<<dim3(QSPLIT, NN / 64, BB), 256, 0, stream>>>(xin, xx, hlv, hlj, C);
        topk_merge_kernel<<<(int)(PTS / 256), 256, 0, stream>>>(hlv, hlj, idx);

        yz_gemm_kernel<<<dim3(2 * co / 64, (int)(PTS / 64)), 256, 0, stream>>>(
            xin, w, y, z, C, co);
        edge_apply_kernel<<<(int)PTS, co, 0, stream>>>(y, z, idx, g, be, rm, rv, xout[l], co);
        xin = xout[l];
    }

    gmax_partial<<<dim3(NSPLIT, BB), 512, 0, stream>>>(x1, x2, x3, x4, part);
    gmax_final<<<BB, 512, 0, stream>>>(part, xg);
    linear_kernel<<<dim3(1024 / 256, BB), 256, 0, stream>>>(
        xg, lin_w, lin_b, g5, b5, rm5, rv5, (float*)d_out);
    transpose_kernel<<<dim3(NN / 32, 256 / 32, BB), dim3(32, 8), 0, stream>>>(
        x4, (float*)d_out + (size_t)BB * 1024);
}

// Round 6
// 1445.546 us; speedup vs baseline: 1.4860x; 1.0131x over previous
//
#include <hip/hip_runtime.h>
#include <hip/hip_bf16.h>
#include <math.h>

#define BB 8
#define NN 2048
#define KK 10
#define QSPLIT 4
#define JT_PER (NN / 64 / QSPLIT)   // 8 j-tiles per block
#define EPSF 1e-5f
#define NEG_SLOPE 0.2f

// ---------------- xx[n] = sum_c x[n,c]^2 ----------------
__global__ void xx_kernel(const float* __restrict__ x, float* __restrict__ xx, int C) {
    int i = blockIdx.x * blockDim.x + threadIdx.x;
    if (i >= BB * NN) return;
    const float* row = x + (size_t)i * C;
    float s = 0.f;
    for (int c = 0; c < C; ++c) { float v = row[c]; s = fmaf(v, v, s); }
    xx[i] = s;
}

// ---------------- fused dist GEMM + exact top-10 (register lists) ----------------
// Block = (j-quarter, i-tile of 64 rows, batch). Streams 8 j-tiles of 64.
// GEMM phase: identical fma order/association as round-3 dist_gemm ->
// bit-identical dist values -> identical neighbor ordering.
// Update phase: 4 threads per row; thread q owns columns {q+4s} of the Ds
// tile (stride-4 -> exact 2-way LDS banking = free) and a per-thread sorted
// top-10 in registers (value desc, index asc). Every candidate does an
// UNCONDITIONAL branch-free sorted-insert (~80 predicated VALU ops):
// rounds 4/5 showed wave-any gating is useless here (27% per-lane insert
// density x 64 lanes => gate fires ~always, paying body + scaffolding).
// End: 4-pointer in-LDS merge -> one sorted 10-list per (row, quarter).
__global__ __launch_bounds__(256) void knn_fused_kernel(
    const float* __restrict__ x, const float* __restrict__ xx,
    float* __restrict__ hlv, int* __restrict__ hlj, int C) {
    int b = blockIdx.z;
    int i0 = blockIdx.y << 6;
    int qs = blockIdx.x;
    const float* xb = x + (size_t)b * NN * C;
    const float* xxb = xx + (size_t)b * NN;
    __shared__ union {
        struct { float As[16][68]; float Bs[16][68]; float Ds[64][68]; } g;
        struct { float Mv[64][4 * KK]; int Mj[64][4 * KK]; } m;
    } S;
    int tid = threadIdx.x;
    int tx = tid & 15, ty = tid >> 4;      // GEMM mapping
    int row = tid >> 2, q = tid & 3;       // update mapping (same wave owns same rows)

    float lv[KK]; int lj[KK];
    #pragma unroll
    for (int e = 0; e < KK; ++e) { lv[e] = -INFINITY; lj[e] = 0x7fffffff; }

    float xi[4];
    #pragma unroll
    for (int u = 0; u < 4; ++u) xi[u] = xxb[i0 + (ty << 2) + u];

    for (int jt = 0; jt < JT_PER; ++jt) {
        int j0 = ((qs * JT_PER + jt) << 6);
        float acc[4][4] = {};
        for (int k0 = 0; k0 < C; k0 += 16) {
            #pragma unroll
            for (int l = tid; l < 1024; l += 256) {
                int r = l >> 4, c = l & 15;
                int kc = k0 + c;
                S.g.As[c][r] = (kc < C) ? xb[(size_t)(i0 + r) * C + kc] : 0.f;
                S.g.Bs[c][r] = (kc < C) ? xb[(size_t)(j0 + r) * C + kc] : 0.f;
            }
            __syncthreads();
            #pragma unroll
            for (int kk = 0; kk < 16; ++kk) {
                float4 a4 = *(const float4*)&S.g.As[kk][ty << 2];
                float4 b4 = *(const float4*)&S.g.Bs[kk][tx << 2];
                float a[4] = {a4.x, a4.y, a4.z, a4.w};
                float bv[4] = {b4.x, b4.y, b4.z, b4.w};
                #pragma unroll
                for (int u = 0; u < 4; ++u)
                    #pragma unroll
                    for (int v = 0; v < 4; ++v)
                        acc[u][v] = fmaf(a[u], bv[v], acc[u][v]);
            }
            __syncthreads();
        }
        float xj[4];
        #pragma unroll
        for (int v = 0; v < 4; ++v) xj[v] = xxb[j0 + (tx << 2) + v];
        #pragma unroll
        for (int u = 0; u < 4; ++u) {
            int rw = (ty << 2) + u;
            float4 o;
            o.x = 2.f * acc[u][0] - xi[u] - xj[0];
            o.y = 2.f * acc[u][1] - xi[u] - xj[1];
            o.z = 2.f * acc[u][2] - xi[u] - xj[2];
            o.w = 2.f * acc[u][3] - xi[u] - xj[3];
            *(float4*)&S.g.Ds[rw][tx << 2] = o;
        }
        __syncthreads();

        // uniform branch-free scan+insert of 16 owned columns (stride 4)
        #pragma unroll
        for (int s = 0; s < 16; ++s) {
            float cv = S.g.Ds[row][(s << 2) + q];
            int cj = j0 + (s << 2) + q;
            bool bt[KK];
            #pragma unroll
            for (int e = 0; e < KK; ++e)
                bt[e] = (cv > lv[e]) || (cv == lv[e] && cj < lj[e]);
            #pragma unroll
            for (int e = KK - 1; e > 0; --e) {
                lv[e] = bt[e] ? (bt[e - 1] ? lv[e - 1] : cv) : lv[e];
                lj[e] = bt[e] ? (bt[e - 1] ? lj[e - 1] : cj) : lj[e];
            }
            lv[0] = bt[0] ? cv : lv[0];
            lj[0] = bt[0] ? cj : lj[0];
        }
        __syncthreads();   // retire Ds reads before next tile overwrites
    }

    // ---- merge 4 thread-lists per row -> sorted quarter list ----
    __syncthreads();       // retire all aliased As/Bs/Ds use before Mv/Mj
    #pragma unroll
    for (int e = 0; e < KK; ++e) {
        S.m.Mv[row][q * KK + e] = lv[e];
        S.m.Mj[row][q * KK + e] = lj[e];
    }
    __syncthreads();
    if (q == 0) {
        float hv[4]; int hj[4]; int p[4];
        #pragma unroll
        for (int e = 0; e < 4; ++e) {
            p[e] = 0;
            hv[e] = S.m.Mv[row][e * KK];
            hj[e] = S.m.Mj[row][e * KK];
        }
        size_t base = (((size_t)b * NN + i0 + row) * QSPLIT + qs) * KK;
        for (int r = 0; r < KK; ++r) {
            float bv = hv[0]; int bj = hj[0]; int L = 0;
            #pragma unroll
            for (int e = 1; e < 4; ++e) {
                bool bt = (hv[e] > bv) || (hv[e] == bv && hj[e] < bj);
                bv = bt ? hv[e] : bv; bj = bt ? hj[e] : bj; L = bt ? e : L;
            }
            hlv[base + r] = bv;
            hlj[base + r] = bj;
            #pragma unroll
            for (int e = 0; e < 4; ++e) {
                if (e == L) {
                    ++p[e];
                    bool ok = p[e] < KK;
                    hv[e] = ok ? S.m.Mv[row][e * KK + p[e]] : -INFINITY;
                    hj[e] = ok ? S.m.Mj[row][e * KK + p[e]] : 0x7fffffff;
                }
            }
        }
    }
}

// ---------------- final merge: 4 sorted quarter-lists -> top-10 indices ----------------
// Quarters cover disjoint j ranges; top-10 of union of quarter top-10s is exact.
__global__ __launch_bounds__(256) void topk_merge_kernel(
    const float* __restrict__ hlv, const int* __restrict__ hlj,
    int* __restrict__ idxout) {
    int row = blockIdx.x * 256 + threadIdx.x;   // [0, BB*NN)
    size_t base = (size_t)row * (QSPLIT * KK);
    float hv[QSPLIT]; int hj[QSPLIT]; int p[QSPLIT];
    #pragma unroll
    for (int e = 0; e < QSPLIT; ++e) {
        p[e] = 0;
        hv[e] = hlv[base + e * KK];
        hj[e] = hlj[base + e * KK];
    }
    int* out = idxout + (size_t)row * KK;
    for (int r = 0; r < KK; ++r) {
        float bv = hv[0]; int bj = hj[0]; int L = 0;
        #pragma unroll
        for (int e = 1; e < QSPLIT; ++e) {
            bool bt = (hv[e] > bv) || (hv[e] == bv && hj[e] < bj);
            bv = bt ? hv[e] : bv; bj = bt ? hj[e] : bj; L = bt ? e : L;
        }
        out[r] = bj;
        #pragma unroll
        for (int e = 0; e < QSPLIT; ++e) {
            if (e == L) {
                ++p[e];
                bool ok = p[e] < KK;
                hv[e] = ok ? hlv[base + e * KK + p[e]] : -INFINITY;
                hj[e] = ok ? hlj[base + e * KK + p[e]] : 0x7fffffff;
            }
        }
    }
}

// ---------------- y,z = X*W1^T, X*W2^T as one tiled GEMM ----------------
__global__ __launch_bounds__(256) void yz_gemm_kernel(
    const float* __restrict__ x, const float* __restrict__ w,
    float* __restrict__ y, float* __restrict__ z, int C, int co) {
    int n0 = blockIdx.y << 6;     // point tile
    int oc0 = blockIdx.x << 6;    // combined output-channel tile
    __shared__ float As[16][68], Bs[16][68];
    int tid = threadIdx.x;
    int tx = tid & 15, ty = tid >> 4;
    float acc[4][4] = {};
    for (int k0 = 0; k0 < C; k0 += 16) {
        #pragma unroll
        for (int l = tid; l < 1024; l += 256) {
            int r = l >> 4, c = l & 15;
            int kc = k0 + c;
            As[c][r] = (kc < C) ? x[(size_t)(n0 + r) * C + kc] : 0.f;
            float bvv = 0.f;
            if (kc < C) {
                int oc = oc0 + r;
                int wrow = (oc < co) ? oc : (oc - co);
                int wcol = (oc < co) ? kc : (C + kc);
                bvv = w[(size_t)wrow * 2 * C + wcol];
            }
            Bs[c][r] = bvv;
        }
        __syncthreads();
        #pragma unroll
        for (int kk = 0; kk < 16; ++kk) {
            float4 a4 = *(const float4*)&As[kk][ty << 2];
            float4 b4 = *(const float4*)&Bs[kk][tx << 2];
            float a[4] = {a4.x, a4.y, a4.z, a4.w};
            float bv[4] = {b4.x, b4.y, b4.z, b4.w};
            #pragma unroll
            for (int u = 0; u < 4; ++u)
                #pragma unroll
                for (int v = 0; v < 4; ++v)
                    acc[u][v] = fmaf(a[u], bv[v], acc[u][v]);
        }
        __syncthreads();
    }
    bool isY = (oc0 < co);
    float* dst = isY ? y : z;
    int c0 = isY ? oc0 : (oc0 - co);
    #pragma unroll
    for (int u = 0; u < 4; ++u) {
        int n = n0 + (ty << 2) + u;
        float4 o;
        o.x = acc[u][0]; o.y = acc[u][1]; o.z = acc[u][2]; o.w = acc[u][3];
        *(float4*)&dst[(size_t)n * co + c0 + (tx << 2)] = o;
    }
}

// ---------------- gather + max_k + BN + lrelu ----------------
__global__ void edge_apply_kernel(const float* __restrict__ y, const float* __restrict__ z,
    const int* __restrict__ idx, const float* __restrict__ g, const float* __restrict__ be,
    const float* __restrict__ rm, const float* __restrict__ rv,
    float* __restrict__ out, int co) {
    int n = blockIdx.x;   // global point id in [0, B*N)
    int o = threadIdx.x;
    int b = n >> 11;      // N = 2048
    __shared__ int sj[KK];
    if (o < KK) sj[o] = idx[(size_t)n * KK + o];
    __syncthreads();
    float yn = y[(size_t)n * co + o], zn = z[(size_t)n * co + o];
    float mx = -INFINITY, mn = INFINITY;
    #pragma unroll
    for (int j = 0; j < KK; ++j) {
        float v = y[((size_t)b * NN + sj[j]) * co + o];
        mx = fmaxf(mx, v);
        mn = fminf(mn, v);
    }
    float s = g[o] * rsqrtf(rv[o] + EPSF);
    float tt = be[o] - rm[o] * s;
    float ybest = (s >= 0.f) ? mx : mn;
    float h = fmaf(s, ybest - yn + zn, tt);
    out[(size_t)n * co + o] = (h >= 0.f) ? h : NEG_SLOPE * h;
}

// ---------------- global max over N of concat(x1..x4) ----------------
#define NSPLIT 32
__global__ void gmax_partial(const float* __restrict__ x1, const float* __restrict__ x2,
                             const float* __restrict__ x3, const float* __restrict__ x4,
                             float* __restrict__ part) {
    int ch = threadIdx.x;            // 0..511
    int split = blockIdx.x, b = blockIdx.y;
    int n0 = split * (NN / NSPLIT);
    float m = -INFINITY;
    for (int q = 0; q < NN / NSPLIT; ++q) {
        int n = b * NN + n0 + q;
        float v;
        if (ch < 64)       v = x1[(size_t)n * 64 + ch];
        else if (ch < 128) v = x2[(size_t)n * 64 + (ch - 64)];
        else if (ch < 256) v = x3[(size_t)n * 128 + (ch - 128)];
        else               v = x4[(size_t)n * 256 + (ch - 256)];
        m = fmaxf(m, v);
    }
    part[((size_t)split * BB + b) * 512 + ch] = m;
}

__global__ void gmax_final(const float* __restrict__ part, float* __restrict__ xg) {
    int ch = threadIdx.x, b = blockIdx.x;
    float m = -INFINITY;
    for (int s = 0; s < NSPLIT; ++s) m = fmaxf(m, part[((size_t)s * BB + b) * 512 + ch]);
    xg[(size_t)b * 512 + ch] = m;
}

// ---------------- final linear + BN + lrelu ----------------
__global__ void linear_kernel(const float* __restrict__ xg, const float* __restrict__ lw,
    const float* __restrict__ lb, const float* __restrict__ g5, const float* __restrict__ b5,
    const float* __restrict__ rm5, const float* __restrict__ rv5, float* __restrict__ out0) {
    int o = blockIdx.x * 256 + threadIdx.x;
    int b = blockIdx.y;
    __shared__ float xs[512];
    for (int l = threadIdx.x; l < 512; l += 256) xs[l] = xg[(size_t)b * 512 + l];
    __syncthreads();
    float acc = 0.f;
    const float* wr = lw + (size_t)o * 512;
    for (int c = 0; c < 512; ++c) acc = fmaf(xs[c], wr[c], acc);
    acc += lb[o];
    float s = g5[o] * rsqrtf(rv5[o] + EPSF);
    float h = fmaf(s, acc - rm5[o], b5[o]);
    out0[(size_t)b * 1024 + o] = (h >= 0.f) ? h : NEG_SLOPE * h;
}

// ---------------- x4 (B,N,256) -> out1 (B,256,N) ----------------
__global__ void transpose_kernel(const float* __restrict__ x4, float* __restrict__ out1) {
    __shared__ float tile[32][33];
    int b = blockIdx.z;
    int nb = blockIdx.x * 32, ob = blockIdx.y * 32;
    int tx = threadIdx.x, ty = threadIdx.y;  // (32, 8)
    #pragma unroll
    for (int r = 0; r < 4; ++r) {
        int o = ob + tx;
        int n = nb + ty + r * 8;
        tile[ty + r * 8][tx] = x4[((size_t)b * NN + n) * 256 + o];
    }
    __syncthreads();
    #pragma unroll
    for (int r = 0; r < 4; ++r) {
        int n = nb + tx;
        int o = ob + ty + r * 8;
        out1[((size_t)b * 256 + o) * NN + n] = tile[tx][ty + r * 8];
    }
}

extern "C" void kernel_launch(void* const* d_in, const int* in_sizes, int n_in,
                              void* d_out, int out_size, void* d_ws, size_t ws_size,
                              hipStream_t stream) {
    const float* x = (const float*)d_in[0];
    const float* lin_w = (const float*)d_in[21];
    const float* lin_b = (const float*)d_in[22];
    const float* g5 = (const float*)d_in[23];
    const float* b5 = (const float*)d_in[24];
    const float* rm5 = (const float*)d_in[25];
    const float* rv5 = (const float*)d_in[26];

    // ---- workspace bump allocation ----
    size_t off = 0;
    auto alloc = [&](size_t nbytes) {
        void* r = (char*)d_ws + off;
        off += (nbytes + 255) & ~(size_t)255;
        return r;
    };
    const size_t PTS = (size_t)BB * NN;
    float* xx   = (float*)alloc(PTS * 4);
    int*   idx  = (int*)  alloc(PTS * KK * 4);
    float* y    = (float*)alloc(PTS * 256 * 4);
    float* z    = (float*)alloc(PTS * 256 * 4);
    float* x1   = (float*)alloc(PTS * 64 * 4);
    float* x2   = (float*)alloc(PTS * 64 * 4);
    float* x3   = (float*)alloc(PTS * 128 * 4);
    float* x4   = (float*)alloc(PTS * 256 * 4);
    float* part = (float*)alloc((size_t)NSPLIT * BB * 512 * 4);
    float* xg   = (float*)alloc((size_t)BB * 512 * 4);
    float* hlv  = (float*)alloc(PTS * QSPLIT * KK * 4);
    int*   hlj  = (int*)  alloc(PTS * QSPLIT * KK * 4);

    const int CI[4] = {5, 64, 64, 128};
    const int CO[4] = {64, 64, 128, 256};
    const float* xin = x;
    float* xout[4] = {x1, x2, x3, x4};

    for (int l = 0; l < 4; ++l) {
        int C = CI[l], co = CO[l];
        const float* w  = (const float*)d_in[1 + l * 5 + 0];
        const float* g  = (const float*)d_in[1 + l * 5 + 1];
        const float* be = (const float*)d_in[1 + l * 5 + 2];
        const float* rm = (const float*)d_in[1 + l * 5 + 3];
        const float* rv = (const float*)d_in[1 + l * 5 + 4];

        xx_kernel<<<(BB * NN + 255) / 256, 256, 0, stream>>>(xin, xx, C);
        knn_fused_kernel<<<dim3(QSPLIT, NN / 64, BB), 256, 0, stream>>>(xin, xx, hlv, hlj, C);
        topk_merge_kernel<<<(int)(PTS / 256), 256, 0, stream>>>(hlv, hlj, idx);

        yz_gemm_kernel<<<dim3(2 * co / 64, (int)(PTS / 64)), 256, 0, stream>>>(
            xin, w, y, z, C, co);
        edge_apply_kernel<<<(int)PTS, co, 0, stream>>>(y, z, idx, g, be, rm, rv, xout[l], co);
        xin = xout[l];
    }

    gmax_partial<<<dim3(NSPLIT, BB), 512, 0, stream>>>(x1, x2, x3, x4, part);
    gmax_final<<<BB, 512, 0, stream>>>(part, xg);
    linear_kernel<<<dim3(1024 / 256, BB), 256, 0, stream>>>(
        xg, lin_w, lin_b, g5, b5, rm5, rv5, (float*)d_out);
    transpose_kernel<<<dim3(NN / 32, 256 / 32, BB), dim3(32, 8), 0, stream>>>(
        x4, (float*)d_out + (size_t)BB * 1024);
}

// Round 7
// 1229.745 us; speedup vs baseline: 1.7468x; 1.1755x over previous
//
#include <hip/hip_runtime.h>
#include <hip/hip_bf16.h>
#include <math.h>

#define BB 8
#define NN 2048
#define KK 10
#define QSPLIT 32                   // one 64-col j-slice per block -> 8192 blocks
#define EPSF 1e-5f
#define NEG_SLOPE 0.2f

// ---------------- xx[n] = sum_c x[n,c]^2 ----------------
__global__ void xx_kernel(const float* __restrict__ x, float* __restrict__ xx, int C) {
    int i = blockIdx.x * blockDim.x + threadIdx.x;
    if (i >= BB * NN) return;
    const float* row = x + (size_t)i * C;
    float s = 0.f;
    for (int c = 0; c < C; ++c) { float v = row[c]; s = fmaf(v, v, s); }
    xx[i] = s;
}

// ---------------- fused dist GEMM + per-slice exact top-10 ----------------
// Block = (j-slice of 64, i-tile of 64 rows, batch) -> 8192 blocks = 32/CU,
// the SAME oversubscription that made round-3's unfused dist_gemm fast.
// (Rounds 4-6 fused with 1024 blocks = 4/CU: one residency batch, barriers
// and insert dep-chains fully exposed -> 414us C-independent pedestal.)
// GEMM phase: identical fma order/association as round-3 dist_gemm ->
// bit-identical dist values -> identical neighbor ordering.
// Update phase: 4 threads per row; thread q owns columns {q+4s} (stride-4 ->
// 2-way LDS banking = free), 16 candidates each, unconditional branch-free
// sorted-insert into a register top-10. Value-only compare (cv > lv[e]) is
// exact: candidates arrive in ascending j, so stable insertion == (v desc,
// j asc) order; cross-thread ties resolved by the merges' explicit j compare.
// End: 4-pointer in-LDS merge -> one sorted 10-list per (row, slice).
__global__ __launch_bounds__(256) void knn_fused_kernel(
    const float* __restrict__ x, const float* __restrict__ xx,
    float* __restrict__ hlv, int* __restrict__ hlj, int C) {
    int b = blockIdx.z;
    int i0 = blockIdx.y << 6;
    int qs = blockIdx.x;
    const float* xb = x + (size_t)b * NN * C;
    const float* xxb = xx + (size_t)b * NN;
    __shared__ union {
        struct { float As[16][68]; float Bs[16][68]; float Ds[64][68]; } g;
        struct { float Mv[64][4 * KK]; int Mj[64][4 * KK]; } m;
    } S;
    int tid = threadIdx.x;
    int tx = tid & 15, ty = tid >> 4;      // GEMM mapping
    int row = tid >> 2, q = tid & 3;       // update mapping (same wave owns same rows)

    float lv[KK]; int lj[KK];
    #pragma unroll
    for (int e = 0; e < KK; ++e) { lv[e] = -INFINITY; lj[e] = 0x7fffffff; }

    float xi[4];
    #pragma unroll
    for (int u = 0; u < 4; ++u) xi[u] = xxb[i0 + (ty << 2) + u];

    int j0 = qs << 6;
    float acc[4][4] = {};
    for (int k0 = 0; k0 < C; k0 += 16) {
        #pragma unroll
        for (int l = tid; l < 1024; l += 256) {
            int r = l >> 4, c = l & 15;
            int kc = k0 + c;
            S.g.As[c][r] = (kc < C) ? xb[(size_t)(i0 + r) * C + kc] : 0.f;
            S.g.Bs[c][r] = (kc < C) ? xb[(size_t)(j0 + r) * C + kc] : 0.f;
        }
        __syncthreads();
        #pragma unroll
        for (int kk = 0; kk < 16; ++kk) {
            float4 a4 = *(const float4*)&S.g.As[kk][ty << 2];
            float4 b4 = *(const float4*)&S.g.Bs[kk][tx << 2];
            float a[4] = {a4.x, a4.y, a4.z, a4.w};
            float bv[4] = {b4.x, b4.y, b4.z, b4.w};
            #pragma unroll
            for (int u = 0; u < 4; ++u)
                #pragma unroll
                for (int v = 0; v < 4; ++v)
                    acc[u][v] = fmaf(a[u], bv[v], acc[u][v]);
        }
        __syncthreads();
    }
    float xj[4];
    #pragma unroll
    for (int v = 0; v < 4; ++v) xj[v] = xxb[j0 + (tx << 2) + v];
    #pragma unroll
    for (int u = 0; u < 4; ++u) {
        int rw = (ty << 2) + u;
        float4 o;
        o.x = 2.f * acc[u][0] - xi[u] - xj[0];
        o.y = 2.f * acc[u][1] - xi[u] - xj[1];
        o.z = 2.f * acc[u][2] - xi[u] - xj[2];
        o.w = 2.f * acc[u][3] - xi[u] - xj[3];
        *(float4*)&S.g.Ds[rw][tx << 2] = o;
    }
    __syncthreads();

    // branch-free scan+insert of 16 owned columns (stride 4, ascending j)
    #pragma unroll
    for (int s = 0; s < 16; ++s) {
        float cv = S.g.Ds[row][(s << 2) + q];
        int cj = j0 + (s << 2) + q;
        bool bt[KK];
        #pragma unroll
        for (int e = 0; e < KK; ++e) bt[e] = (cv > lv[e]);
        #pragma unroll
        for (int e = KK - 1; e > 0; --e) {
            lv[e] = bt[e] ? (bt[e - 1] ? lv[e - 1] : cv) : lv[e];
            lj[e] = bt[e] ? (bt[e - 1] ? lj[e - 1] : cj) : lj[e];
        }
        lv[0] = bt[0] ? cv : lv[0];
        lj[0] = bt[0] ? cj : lj[0];
    }

    // ---- merge 4 thread-lists per row -> sorted slice list ----
    __syncthreads();       // retire all aliased As/Bs/Ds use before Mv/Mj
    #pragma unroll
    for (int e = 0; e < KK; ++e) {
        S.m.Mv[row][q * KK + e] = lv[e];
        S.m.Mj[row][q * KK + e] = lj[e];
    }
    __syncthreads();
    if (q == 0) {
        float hv[4]; int hj[4]; int p[4];
        #pragma unroll
        for (int e = 0; e < 4; ++e) {
            p[e] = 0;
            hv[e] = S.m.Mv[row][e * KK];
            hj[e] = S.m.Mj[row][e * KK];
        }
        size_t base = (((size_t)b * NN + i0 + row) * QSPLIT + qs) * KK;
        for (int r = 0; r < KK; ++r) {
            float bv = hv[0]; int bj = hj[0]; int L = 0;
            #pragma unroll
            for (int e = 1; e < 4; ++e) {
                bool bt = (hv[e] > bv) || (hv[e] == bv && hj[e] < bj);
                bv = bt ? hv[e] : bv; bj = bt ? hj[e] : bj; L = bt ? e : L;
            }
            hlv[base + r] = bv;
            hlj[base + r] = bj;
            #pragma unroll
            for (int e = 0; e < 4; ++e) {
                if (e == L) {
                    ++p[e];
                    bool ok = p[e] < KK;
                    hv[e] = ok ? S.m.Mv[row][e * KK + p[e]] : -INFINITY;
                    hj[e] = ok ? S.m.Mj[row][e * KK + p[e]] : 0x7fffffff;
                }
            }
        }
    }
}

// ---------------- final merge: 32 sorted slice-lists -> top-10 indices ----------------
// Slices cover disjoint j ranges; top-10 of union of slice top-10s is exact.
// 32-pointer register merge, statically unrolled (no dynamic indexing).
__global__ __launch_bounds__(64) void topk_merge_kernel(
    const float* __restrict__ hlv, const int* __restrict__ hlj,
    int* __restrict__ idxout) {
    int row = blockIdx.x * 64 + threadIdx.x;   // [0, BB*NN)
    size_t base = (size_t)row * (QSPLIT * KK);
    float hv[QSPLIT]; int hj[QSPLIT]; int p[QSPLIT];
    #pragma unroll
    for (int e = 0; e < QSPLIT; ++e) {
        p[e] = 0;
        hv[e] = hlv[base + e * KK];
        hj[e] = hlj[base + e * KK];
    }
    int* out = idxout + (size_t)row * KK;
    for (int r = 0; r < KK; ++r) {
        float bv = hv[0]; int bj = hj[0]; int L = 0;
        #pragma unroll
        for (int e = 1; e < QSPLIT; ++e) {
            bool bt = (hv[e] > bv) || (hv[e] == bv && hj[e] < bj);
            bv = bt ? hv[e] : bv; bj = bt ? hj[e] : bj; L = bt ? e : L;
        }
        out[r] = bj;
        #pragma unroll
        for (int e = 0; e < QSPLIT; ++e) {
            if (e == L) {
                ++p[e];
                bool ok = p[e] < KK;
                hv[e] = ok ? hlv[base + e * KK + p[e]] : -INFINITY;
                hj[e] = ok ? hlj[base + e * KK + p[e]] : 0x7fffffff;
            }
        }
    }
}

// ---------------- y,z = X*W1^T, X*W2^T as one tiled GEMM ----------------
__global__ __launch_bounds__(256) void yz_gemm_kernel(
    const float* __restrict__ x, const float* __restrict__ w,
    float* __restrict__ y, float* __restrict__ z, int C, int co) {
    int n0 = blockIdx.y << 6;     // point tile
    int oc0 = blockIdx.x << 6;    // combined output-channel tile
    __shared__ float As[16][68], Bs[16][68];
    int tid = threadIdx.x;
    int tx = tid & 15, ty = tid >> 4;
    float acc[4][4] = {};
    for (int k0 = 0; k0 < C; k0 += 16) {
        #pragma unroll
        for (int l = tid; l < 1024; l += 256) {
            int r = l >> 4, c = l & 15;
            int kc = k0 + c;
            As[c][r] = (kc < C) ? x[(size_t)(n0 + r) * C + kc] : 0.f;
            float bvv = 0.f;
            if (kc < C) {
                int oc = oc0 + r;
                int wrow = (oc < co) ? oc : (oc - co);
                int wcol = (oc < co) ? kc : (C + kc);
                bvv = w[(size_t)wrow * 2 * C + wcol];
            }
            Bs[c][r] = bvv;
        }
        __syncthreads();
        #pragma unroll
        for (int kk = 0; kk < 16; ++kk) {
            float4 a4 = *(const float4*)&As[kk][ty << 2];
            float4 b4 = *(const float4*)&Bs[kk][tx << 2];
            float a[4] = {a4.x, a4.y, a4.z, a4.w};
            float bv[4] = {b4.x, b4.y, b4.z, b4.w};
            #pragma unroll
            for (int u = 0; u < 4; ++u)
                #pragma unroll
                for (int v = 0; v < 4; ++v)
                    acc[u][v] = fmaf(a[u], bv[v], acc[u][v]);
        }
        __syncthreads();
    }
    bool isY = (oc0 < co);
    float* dst = isY ? y : z;
    int c0 = isY ? oc0 : (oc0 - co);
    #pragma unroll
    for (int u = 0; u < 4; ++u) {
        int n = n0 + (ty << 2) + u;
        float4 o;
        o.x = acc[u][0]; o.y = acc[u][1]; o.z = acc[u][2]; o.w = acc[u][3];
        *(float4*)&dst[(size_t)n * co + c0 + (tx << 2)] = o;
    }
}

// ---------------- gather + max_k + BN + lrelu ----------------
__global__ void edge_apply_kernel(const float* __restrict__ y, const float* __restrict__ z,
    const int* __restrict__ idx, const float* __restrict__ g, const float* __restrict__ be,
    const float* __restrict__ rm, const float* __restrict__ rv,
    float* __restrict__ out, int co) {
    int n = blockIdx.x;   // global point id in [0, B*N)
    int o = threadIdx.x;
    int b = n >> 11;      // N = 2048
    __shared__ int sj[KK];
    if (o < KK) sj[o] = idx[(size_t)n * KK + o];
    __syncthreads();
    float yn = y[(size_t)n * co + o], zn = z[(size_t)n * co + o];
    float mx = -INFINITY, mn = INFINITY;
    #pragma unroll
    for (int j = 0; j < KK; ++j) {
        float v = y[((size_t)b * NN + sj[j]) * co + o];
        mx = fmaxf(mx, v);
        mn = fminf(mn, v);
    }
    float s = g[o] * rsqrtf(rv[o] + EPSF);
    float tt = be[o] - rm[o] * s;
    float ybest = (s >= 0.f) ? mx : mn;
    float h = fmaf(s, ybest - yn + zn, tt);
    out[(size_t)n * co + o] = (h >= 0.f) ? h : NEG_SLOPE * h;
}

// ---------------- global max over N of concat(x1..x4) ----------------
#define NSPLIT 32
__global__ void gmax_partial(const float* __restrict__ x1, const float* __restrict__ x2,
                             const float* __restrict__ x3, const float* __restrict__ x4,
                             float* __restrict__ part) {
    int ch = threadIdx.x;            // 0..511
    int split = blockIdx.x, b = blockIdx.y;
    int n0 = split * (NN / NSPLIT);
    float m = -INFINITY;
    for (int q = 0; q < NN / NSPLIT; ++q) {
        int n = b * NN + n0 + q;
        float v;
        if (ch < 64)       v = x1[(size_t)n * 64 + ch];
        else if (ch < 128) v = x2[(size_t)n * 64 + (ch - 64)];
        else if (ch < 256) v = x3[(size_t)n * 128 + (ch - 128)];
        else               v = x4[(size_t)n * 256 + (ch - 256)];
        m = fmaxf(m, v);
    }
    part[((size_t)split * BB + b) * 512 + ch] = m;
}

__global__ void gmax_final(const float* __restrict__ part, float* __restrict__ xg) {
    int ch = threadIdx.x, b = blockIdx.x;
    float m = -INFINITY;
    for (int s = 0; s < NSPLIT; ++s) m = fmaxf(m, part[((size_t)s * BB + b) * 512 + ch]);
    xg[(size_t)b * 512 + ch] = m;
}

// ---------------- final linear + BN + lrelu ----------------
__global__ void linear_kernel(const float* __restrict__ xg, const float* __restrict__ lw,
    const float* __restrict__ lb, const float* __restrict__ g5, const float* __restrict__ b5,
    const float* __restrict__ rm5, const float* __restrict__ rv5, float* __restrict__ out0) {
    int o = blockIdx.x * 256 + threadIdx.x;
    int b = blockIdx.y;
    __shared__ float xs[512];
    for (int l = threadIdx.x; l < 512; l += 256) xs[l] = xg[(size_t)b * 512 + l];
    __syncthreads();
    float acc = 0.f;
    const float* wr = lw + (size_t)o * 512;
    for (int c = 0; c < 512; ++c) acc = fmaf(xs[c], wr[c], acc);
    acc += lb[o];
    float s = g5[o] * rsqrtf(rv5[o] + EPSF);
    float h = fmaf(s, acc - rm5[o], b5[o]);
    out0[(size_t)b * 1024 + o] = (h >= 0.f) ? h : NEG_SLOPE * h;
}

// ---------------- x4 (B,N,256) -> out1 (B,256,N) ----------------
__global__ void transpose_kernel(const float* __restrict__ x4, float* __restrict__ out1) {
    __shared__ float tile[32][33];
    int b = blockIdx.z;
    int nb = blockIdx.x * 32, ob = blockIdx.y * 32;
    int tx = threadIdx.x, ty = threadIdx.y;  // (32, 8)
    #pragma unroll
    for (int r = 0; r < 4; ++r) {
        int o = ob + tx;
        int n = nb + ty + r * 8;
        tile[ty + r * 8][tx] = x4[((size_t)b * NN + n) * 256 + o];
    }
    __syncthreads();
    #pragma unroll
    for (int r = 0; r < 4; ++r) {
        int n = nb + tx;
        int o = ob + ty + r * 8;
        out1[((size_t)b * 256 + o) * NN + n] = tile[tx][ty + r * 8];
    }
}

extern "C" void kernel_launch(void* const* d_in, const int* in_sizes, int n_in,
                              void* d_out, int out_size, void* d_ws, size_t ws_size,
                              hipStream_t stream) {
    const float* x = (const float*)d_in[0];
    const float* lin_w = (const float*)d_in[21];
    const float* lin_b = (const float*)d_in[22];
    const float* g5 = (const float*)d_in[23];
    const float* b5 = (const float*)d_in[24];
    const float* rm5 = (const float*)d_in[25];
    const float* rv5 = (const float*)d_in[26];

    // ---- workspace bump allocation ----
    size_t off = 0;
    auto alloc = [&](size_t nbytes) {
        void* r = (char*)d_ws + off;
        off += (nbytes + 255) & ~(size_t)255;
        return r;
    };
    const size_t PTS = (size_t)BB * NN;
    float* xx   = (float*)alloc(PTS * 4);
    int*   idx  = (int*)  alloc(PTS * KK * 4);
    float* y    = (float*)alloc(PTS * 256 * 4);
    float* z    = (float*)alloc(PTS * 256 * 4);
    float* x1   = (float*)alloc(PTS * 64 * 4);
    float* x2   = (float*)alloc(PTS * 64 * 4);
    float* x3   = (float*)alloc(PTS * 128 * 4);
    float* x4   = (float*)alloc(PTS * 256 * 4);
    float* part = (float*)alloc((size_t)NSPLIT * BB * 512 * 4);
    float* xg   = (float*)alloc((size_t)BB * 512 * 4);
    float* hlv  = (float*)alloc(PTS * QSPLIT * KK * 4);
    int*   hlj  = (int*)  alloc(PTS * QSPLIT * KK * 4);

    const int CI[4] = {5, 64, 64, 128};
    const int CO[4] = {64, 64, 128, 256};
    const float* xin = x;
    float* xout[4] = {x1, x2, x3, x4};

    for (int l = 0; l < 4; ++l) {
        int C = CI[l], co = CO[l];
        const float* w  = (const float*)d_in[1 + l * 5 + 0];
        const float* g  = (const float*)d_in[1 + l * 5 + 1];
        const float* be = (const float*)d_in[1 + l * 5 + 2];
        const float* rm = (const float*)d_in[1 + l * 5 + 3];
        const float* rv = (const float*)d_in[1 + l * 5 + 4];

        xx_kernel<<<(BB * NN + 255) / 256, 256, 0, stream>>>(xin, xx, C);
        knn_fused_kernel<<<dim3(QSPLIT, NN / 64, BB), 256, 0, stream>>>(xin, xx, hlv, hlj, C);
        topk_merge_kernel<<<(int)(PTS / 64), 64, 0, stream>>>(hlv, hlj, idx);

        yz_gemm_kernel<<<dim3(2 * co / 64, (int)(PTS / 64)), 256, 0, stream>>>(
            xin, w, y, z, C, co);
        edge_apply_kernel<<<(int)PTS, co, 0, stream>>>(y, z, idx, g, be, rm, rv, xout[l], co);
        xin = xout[l];
    }

    gmax_partial<<<dim3(NSPLIT, BB), 512, 0, stream>>>(x1, x2, x3, x4, part);
    gmax_final<<<BB, 512, 0, stream>>>(part, xg);
    linear_kernel<<<dim3(1024 / 256, BB), 256, 0, stream>>>(
        xg, lin_w, lin_b, g5, b5, rm5, rv5, (float*)d_out);
    transpose_kernel<<<dim3(NN / 32, 256 / 32, BB), dim3(32, 8), 0, stream>>>(
        x4, (float*)d_out + (size_t)BB * 1024);
}